// Round 3
// 1135.797 us; speedup vs baseline: 1.1712x; 1.1712x over previous
//
#include <hip/hip_runtime.h>
#include <math.h>

// Problem constants (fixed by the reference).
#define N_NODES 50000
#define N_EDGES 640000   // divisible by 32 (20000 tiles) and 256
#define NLAYER  4
#define NPAD    50016    // N_NODES rounded up to 32

typedef unsigned short bf16_t;
typedef __attribute__((ext_vector_type(8))) short s16x8;   // 8 bf16 = 4 VGPR (MFMA A/B frag)
typedef __attribute__((ext_vector_type(4))) float f32x4;   // MFMA C/D frag

__device__ __forceinline__ float gelu_f(float x) {
    return 0.5f * x * (1.0f + tanhf(0.7978845608028654f * (x + 0.044715f * x * x * x)));
}

__device__ __forceinline__ bf16_t f2bf(float f) {
    unsigned u = __float_as_uint(f);
    unsigned r = (u + 0x7FFFu + ((u >> 16) & 1u)) >> 16;   // RNE
    return (bf16_t)r;
}
__device__ __forceinline__ float bf2f(bf16_t h) { return __uint_as_float(((unsigned)h) << 16); }
__device__ __forceinline__ float bfl(unsigned x) { return __uint_as_float(x << 16); }
__device__ __forceinline__ float bfh(unsigned x) { return __uint_as_float(x & 0xFFFF0000u); }

// ---------------- CSR build (counting sort by dst) ----------------
__global__ void k_zero32(unsigned* p, int n) {
    int i = blockIdx.x * 256 + threadIdx.x;
    if (i < n) p[i] = 0u;
}

__global__ void k_hist(const int* __restrict__ dst, int* __restrict__ deg) {
    int i = blockIdx.x * 256 + threadIdx.x;
    if (i < N_EDGES) atomicAdd(&deg[dst[i]], 1);
}

__global__ void k_scan1(const int* __restrict__ deg, int* __restrict__ rowptr, int* __restrict__ bsum) {
    __shared__ int sd[1024];
    int gi = blockIdx.x * 1024 + threadIdx.x;
    int v = (gi < N_NODES) ? deg[gi] : 0;
    sd[threadIdx.x] = v;
    __syncthreads();
    for (int off = 1; off < 1024; off <<= 1) {
        int t2 = (threadIdx.x >= (unsigned)off) ? sd[threadIdx.x - off] : 0;
        __syncthreads();
        sd[threadIdx.x] += t2;
        __syncthreads();
    }
    if (gi < N_NODES) rowptr[gi] = sd[threadIdx.x] - v;  // block-local exclusive
    if (threadIdx.x == 1023) bsum[blockIdx.x] = sd[1023];
}

__global__ void k_scan2(const int* __restrict__ bsum, int* __restrict__ boff, int nb) {
    if (threadIdx.x == 0 && blockIdx.x == 0) {
        int run = 0;
        for (int b = 0; b < nb; b++) { boff[b] = run; run += bsum[b]; }
    }
}

__global__ void k_scan3(int* __restrict__ rowptr, const int* __restrict__ boff) {
    int gi = blockIdx.x * 1024 + threadIdx.x;
    if (gi < N_NODES) rowptr[gi] += boff[blockIdx.x];
    if (gi == 0) rowptr[N_NODES] = N_EDGES;
}

__global__ void k_copy(const int* __restrict__ a, int* __restrict__ b) {
    int i = blockIdx.x * 256 + threadIdx.x;
    if (i < N_NODES) b[i] = a[i];
}

__global__ void k_scatter(const int* __restrict__ dst, int* __restrict__ cursor, int* __restrict__ eidx) {
    int i = blockIdx.x * 256 + threadIdx.x;
    if (i < N_EDGES) {
        int p = atomicAdd(&cursor[dst[i]], 1);
        eidx[p] = i;
    }
}

// Gather per-edge fields into dst-sorted order, packed as two uint4 per edge:
// emeta[2i]   = { combo = etype*9+erid, src, dst, rc0 }
// emeta[2i+1] = { rc1, rp0, rp1, rp2 }
__global__ void k_sortgather(
    const int* __restrict__ eidx, const int* __restrict__ src, const int* __restrict__ dst,
    const int* __restrict__ etype, const int* __restrict__ erid,
    const float* __restrict__ att_rc, const float* __restrict__ att_rp,
    int* __restrict__ src_s, uint4* __restrict__ emeta)
{
    int i = blockIdx.x * 256 + threadIdx.x;
    if (i < N_EDGES) {
        int e = eidx[i];
        int sv = src[e];
        src_s[i] = sv;
        uint4 a, b;
        a.x = (unsigned)(etype[e] * 9 + erid[e]);
        a.y = (unsigned)sv;
        a.z = (unsigned)dst[e];
        a.w = __float_as_uint(att_rc[2 * e]);
        b.x = __float_as_uint(att_rc[2 * e + 1]);
        b.y = __float_as_uint(att_rp[3 * e]);
        b.z = __float_as_uint(att_rp[3 * e + 1]);
        b.w = __float_as_uint(att_rp[3 * e + 2]);
        emeta[2 * i] = a;
        emeta[2 * i + 1] = b;
    }
}

// ---------------- (etype,erid)-combo base table: 315 x 64 fp32 (~80 KB, cache-hot) ----------
// base[c][k] = type_emb[et][k] + rid_emb[er][k] + rcb[k] + rpb[k]  (exact old add order)
__global__ void k_base(const float* __restrict__ type_emb, const float* __restrict__ rid_emb,
                       const float* __restrict__ rcb, const float* __restrict__ rpb,
                       float* __restrict__ base)
{
    int idx = blockIdx.x * 256 + threadIdx.x;
    if (idx >= 315 * 64) return;
    int c = idx >> 6, k = idx & 63;
    int et = c / 9, er = c % 9;
    base[idx] = type_emb[et * 64 + k] + rid_emb[er * 64 + k] + rcb[k] + rpb[k];
}

// Weight transposes to bf16, k-contiguous rows (MFMA A-operand friendly).
__global__ void k_wprep(const float* __restrict__ Wfij, const float* __restrict__ Wni,
                        const float* __restrict__ Wnj, const float* __restrict__ Wnode,
                        const float* __restrict__ W1, const float* __restrict__ W2,
                        bf16_t* __restrict__ WT, bf16_t* __restrict__ W3T,
                        bf16_t* __restrict__ W1T, bf16_t* __restrict__ W2T)
{
    int idx = blockIdx.x * 256 + threadIdx.x;
    if (idx >= NLAYER * 57344) return;
    int l = idx / 57344, r = idx % 57344;
    if (r < 8192) {
        int n = r >> 6, k = r & 63;
        WT[l * 8192 + r] = f2bf(Wfij[l * 8192 + k * 128 + n]);
    } else if (r < 32768) {
        int q = r - 8192; int c = q >> 6, k = q & 63;
        const float* src = (c < 128) ? Wni : (c < 256) ? Wnj : Wnode;
        W3T[l * 24576 + q] = f2bf(src[l * 8192 + k * 128 + (c & 127)]);
    } else if (r < 49152) {
        int q = r - 32768; int n = q >> 7, k = q & 127;
        W1T[l * 16384 + q] = f2bf(W1[l * 16384 + k * 128 + n]);
    } else {
        int q = r - 49152; int j = q >> 7, k = q & 127;
        W2T[l * 8192 + q] = f2bf(W2[l * 8192 + k * 64 + j]);
    }
}

// ---------------- feature encoder: h0 = gelu(feat@W1+b1)@W2+b2 ----------------
__global__ __launch_bounds__(256) void k_fe(
    const float* __restrict__ feat, const float* __restrict__ W1, const float* __restrict__ b1,
    const float* __restrict__ W2, const float* __restrict__ b2,
    float* __restrict__ h, bf16_t* __restrict__ hb, float* __restrict__ out)
{
    __shared__ float hid[4][64];
    int w = threadIdx.x >> 6, lane = threadIdx.x & 63;
    int n = blockIdx.x * 4 + w;  // N divisible by 4
    float a = b1[lane];
#pragma unroll 8
    for (int k = 0; k < 32; k++) a = fmaf(feat[n * 32 + k], W1[k * 64 + lane], a);
    hid[w][lane] = gelu_f(a);
    __syncthreads();
    float o = b2[lane];
#pragma unroll 8
    for (int k = 0; k < 64; k++) o = fmaf(hid[w][k], W2[k * 64 + lane], o);
    h[n * 64 + lane] = o;
    hb[n * 64 + lane] = f2bf(o);
    out[n * 704 + 32 + lane] = o;
    if (lane < 32) out[n * 704 + lane] = feat[n * 32 + lane];
}

// ---------------- s = h @ [W_ni | W_nj | W_node(+b)] -> [NPAD,384] bf16, MFMA ----------------
__global__ __launch_bounds__(256) void k_node3(
    const bf16_t* __restrict__ hb, const bf16_t* __restrict__ W3T,
    const float* __restrict__ bnode, bf16_t* __restrict__ s)
{
    __shared__ __align__(16) bf16_t hbS[32 * 72];
    const int t = threadIdx.x;
    const int wave = t >> 6, lane = t & 63, l16 = lane & 15, quad = lane >> 4;
    const int n0 = blockIdx.x * 32;
    {   // stage hb tile: 32 rows x 128B
        int r = t >> 3, sg = t & 7;
        *(s16x8*)(hbS + r * 72 + sg * 8) = *(const s16x8*)(hb + (size_t)(n0 + r) * 64 + sg * 8);
    }
    __syncthreads();
    const int ng = wave & 1, ch = wave >> 1;
    const s16x8 B0 = *(const s16x8*)(hbS + (ng * 16 + l16) * 72 + quad * 8);
    const s16x8 B1 = *(const s16x8*)(hbS + (ng * 16 + l16) * 72 + 32 + quad * 8);
    const int node = n0 + ng * 16 + l16;
#pragma unroll
    for (int nt = 0; nt < 12; nt++) {
        int c0 = ch * 192 + nt * 16;
        const s16x8 A0 = *(const s16x8*)(W3T + (size_t)(c0 + l16) * 64 + quad * 8);
        const s16x8 A1 = *(const s16x8*)(W3T + (size_t)(c0 + l16) * 64 + 32 + quad * 8);
        f32x4 acc = {0.f, 0.f, 0.f, 0.f};
        acc = __builtin_amdgcn_mfma_f32_16x16x32_bf16(A0, B0, acc, 0, 0, 0);
        acc = __builtin_amdgcn_mfma_f32_16x16x32_bf16(A1, B1, acc, 0, 0, 0);
        int cb = c0 + quad * 4;
        float4 bv = make_float4(0.f, 0.f, 0.f, 0.f);
        if (cb >= 256) bv = *(const float4*)(bnode + cb - 256);
        ushort4 o;
        o.x = f2bf(acc[0] + bv.x);
        o.y = f2bf(acc[1] + bv.y);
        o.z = f2bf(acc[2] + bv.z);
        o.w = f2bf(acc[3] + bv.w);
        *(ushort4*)(s + (size_t)node * 384 + cb) = o;
    }
}

// ---------------- fused edge kernel: wave-independent 16-edge tiles, no in-loop barriers --------
// Per wave, lane (l16, quad) owns edge i = tile*16 + l16.
//  - ef recomputed in-register: base[combo] (80 KB fp32 table, cache-hot) + 5-term fma
//    correction from LDS-staged rcW/rpW rows (broadcast reads). Exact old op order.
//  - SND: only consumed dims (mt*16+quad*4, i.e. dims 0..63) gathered directly into the
//    MFMA C-layout positions: 8x8B loads/lane = 256B/edge (2 cache lines), as in R0.
//  - A-frags for BOTH heads hoisted to registers from LDS-staged WT (stride-72 padding).
// Arithmetic (fma order, bf16 round-trips, shuffle reduce) replicates R0 bit-for-bit.
__global__ __launch_bounds__(256) void k_edge(
    const bf16_t* __restrict__ s, const bf16_t* __restrict__ WT,
    const float* __restrict__ attn, const uint4* __restrict__ emeta,
    const float* __restrict__ base, const float* __restrict__ rcW,
    const float* __restrict__ rpW, float* __restrict__ evals)
{
    __shared__ __align__(16) bf16_t WTl[128 * 72];
    __shared__ __align__(16) float attL[128];
    __shared__ __align__(16) float cwL[5][64];
    // Stage WT: 128 rows x 64 bf16 = 1024 x 16B chunks (FIX: was 512 -> half-staged rows).
    for (int c = threadIdx.x; c < 1024; c += 256) {
        int r = c >> 3, q = c & 7;
        *(s16x8*)(WTl + r * 72 + q * 8) = *(const s16x8*)(WT + r * 64 + q * 8);
    }
    if (threadIdx.x < 128) attL[threadIdx.x] = attn[threadIdx.x];
    {
        int j = threadIdx.x >> 6, k = threadIdx.x & 63;    // j in [0,4)
        cwL[j][k] = (j < 2) ? rcW[j * 64 + k] : rpW[(j - 2) * 64 + k];
        if (threadIdx.x < 64) cwL[4][threadIdx.x] = rpW[128 + threadIdx.x];
    }
    __syncthreads();

    const int lane = threadIdx.x & 63;
    const int l16 = lane & 15, quad = lane >> 4;

    // Hoist A-frags for both heads into registers.
    s16x8 Aw[2][4][2];
#pragma unroll
    for (int hd = 0; hd < 2; hd++)
#pragma unroll
        for (int mt = 0; mt < 4; mt++) {
            const bf16_t* arow = WTl + (hd * 64 + mt * 16 + l16) * 72 + quad * 8;
            Aw[hd][mt][0] = *(const s16x8*)(arow);
            Aw[hd][mt][1] = *(const s16x8*)(arow + 32);
        }

    const int nw = (gridDim.x * 256) >> 6;
    for (int tile = (blockIdx.x * 256 + threadIdx.x) >> 6; tile < N_EDGES / 16; tile += nw) {
        const int i = tile * 16 + l16;
        const uint4 m0 = emeta[2 * i];
        const uint4 m1 = emeta[2 * i + 1];

        // Issue the long-latency gathers first.
        const bf16_t* srow = s + (size_t)m0.y * 384;          // ni cols 0..63 used
        const bf16_t* drow = s + (size_t)m0.z * 384 + 128;    // nj cols 0..63 used
        ushort4 niv[4], njv[4];
#pragma unroll
        for (int mt = 0; mt < 4; mt++) {
            const int d0 = mt * 16 + quad * 4;
            niv[mt] = *(const ushort4*)(srow + d0);
            njv[mt] = *(const ushort4*)(drow + d0);
        }

        // ef for this lane's 16 k-dims: base + 5-term correction (exact old op order).
        const float* bp = base + (size_t)m0.x * 64;
        const float4 bv0 = *(const float4*)(bp + quad * 8);
        const float4 bv1 = *(const float4*)(bp + quad * 8 + 4);
        const float4 bv2 = *(const float4*)(bp + 32 + quad * 8);
        const float4 bv3 = *(const float4*)(bp + 32 + quad * 8 + 4);
        const float rc0 = __uint_as_float(m0.w), rc1 = __uint_as_float(m1.x);
        const float rp0 = __uint_as_float(m1.y), rp1 = __uint_as_float(m1.z), rp2 = __uint_as_float(m1.w);

        auto efg = [&](const float4& bv, int k) -> ushort4 {
            const float4 w0 = *(const float4*)(&cwL[0][k]);
            const float4 w1 = *(const float4*)(&cwL[1][k]);
            const float4 w2 = *(const float4*)(&cwL[2][k]);
            const float4 w3 = *(const float4*)(&cwL[3][k]);
            const float4 w4 = *(const float4*)(&cwL[4][k]);
            float v0 = bv.x, v1 = bv.y, v2 = bv.z, v3 = bv.w;
            v0 = fmaf(rc0, w0.x, v0); v1 = fmaf(rc0, w0.y, v1); v2 = fmaf(rc0, w0.z, v2); v3 = fmaf(rc0, w0.w, v3);
            v0 = fmaf(rc1, w1.x, v0); v1 = fmaf(rc1, w1.y, v1); v2 = fmaf(rc1, w1.z, v2); v3 = fmaf(rc1, w1.w, v3);
            v0 = fmaf(rp0, w2.x, v0); v1 = fmaf(rp0, w2.y, v1); v2 = fmaf(rp0, w2.z, v2); v3 = fmaf(rp0, w2.w, v3);
            v0 = fmaf(rp1, w3.x, v0); v1 = fmaf(rp1, w3.y, v1); v2 = fmaf(rp1, w3.z, v2); v3 = fmaf(rp1, w3.w, v3);
            v0 = fmaf(rp2, w4.x, v0); v1 = fmaf(rp2, w4.y, v1); v2 = fmaf(rp2, w4.z, v2); v3 = fmaf(rp2, w4.w, v3);
            ushort4 r;
            r.x = f2bf(v0); r.y = f2bf(v1); r.z = f2bf(v2); r.w = f2bf(v3);
            return r;
        };
        const ushort4 e0 = efg(bv0, quad * 8);
        const ushort4 e1 = efg(bv1, quad * 8 + 4);
        const ushort4 e2 = efg(bv2, 32 + quad * 8);
        const ushort4 e3 = efg(bv3, 32 + quad * 8 + 4);
        s16x8 B0, B1;
        B0[0] = (short)e0.x; B0[1] = (short)e0.y; B0[2] = (short)e0.z; B0[3] = (short)e0.w;
        B0[4] = (short)e1.x; B0[5] = (short)e1.y; B0[6] = (short)e1.z; B0[7] = (short)e1.w;
        B1[0] = (short)e2.x; B1[1] = (short)e2.y; B1[2] = (short)e2.z; B1[3] = (short)e2.w;
        B1[4] = (short)e3.x; B1[5] = (short)e3.y; B1[6] = (short)e3.z; B1[7] = (short)e3.w;

        ushort4 snd[4];
#pragma unroll
        for (int mt = 0; mt < 4; mt++) {   // same bf16 round-trip as R0 SND staging
            snd[mt].x = f2bf(bf2f(niv[mt].x) + bf2f(njv[mt].x));
            snd[mt].y = f2bf(bf2f(niv[mt].y) + bf2f(njv[mt].y));
            snd[mt].z = f2bf(bf2f(niv[mt].z) + bf2f(njv[mt].z));
            snd[mt].w = f2bf(bf2f(niv[mt].w) + bf2f(njv[mt].w));
        }

#pragma unroll
        for (int hd = 0; hd < 2; hd++) {
            float p = 0.f;
#pragma unroll
            for (int mt = 0; mt < 4; mt++) {
                f32x4 a = {0.f, 0.f, 0.f, 0.f};
                a = __builtin_amdgcn_mfma_f32_16x16x32_bf16(Aw[hd][mt][0], B0, a, 0, 0, 0);
                a = __builtin_amdgcn_mfma_f32_16x16x32_bf16(Aw[hd][mt][1], B1, a, 0, 0, 0);
                const float4 at = *(const float4*)(attL + hd * 64 + mt * 16 + quad * 4);
                float f0 = a[0] + bf2f(snd[mt].x);
                float f1 = a[1] + bf2f(snd[mt].y);
                float f2 = a[2] + bf2f(snd[mt].z);
                float f3 = a[3] + bf2f(snd[mt].w);
                f0 = (f0 >= 0.f) ? f0 : 0.2f * f0;
                f1 = (f1 >= 0.f) ? f1 : 0.2f * f1;
                f2 = (f2 >= 0.f) ? f2 : 0.2f * f2;
                f3 = (f3 >= 0.f) ? f3 : 0.2f * f3;
                p = fmaf(f0, at.x, p);
                p = fmaf(f1, at.y, p);
                p = fmaf(f2, at.z, p);
                p = fmaf(f3, at.w, p);
            }
            p += __shfl_xor(p, 16);
            p += __shfl_xor(p, 32);
            if (quad == 0) evals[i * 2 + hd] = p;
        }
    }
}

// ---------------- per-dst softmax + aggregation -> aggb bf16 ----------------
__global__ __launch_bounds__(256) void k_soft_agg(
    const int* __restrict__ rowptr, const int* __restrict__ src_s,
    const float* __restrict__ evals, const bf16_t* __restrict__ s,
    unsigned* __restrict__ aggb)   // [NPAD][64] uints = [NPAD][128] bf16
{
    int lane = threadIdx.x & 63;
    int wid = (blockIdx.x * 256 + threadIdx.x) >> 6;
    int nw = (gridDim.x * 256) >> 6;
    const int h1 = (lane >= 32) ? 1 : 0;
    const int half = lane & 31;
    for (int n = wid; n < N_NODES; n += nw) {
        int r0 = rowptr[n], r1 = rowptr[n + 1];
        unsigned* aout = aggb + (size_t)n * 64 + lane;
        if (r0 == r1) { *aout = 0u; continue; }
        float mm = -1e30f;
        for (int i = r0 + half; i < r1; i += 32) mm = fmaxf(mm, evals[2 * i + h1]);
#pragma unroll
        for (int off = 1; off < 32; off <<= 1) mm = fmaxf(mm, __shfl_xor(mm, off));
        float z = 0.f;
        for (int i = r0 + half; i < r1; i += 32) z += expf(evals[2 * i + h1] - mm);
#pragma unroll
        for (int off = 1; off < 32; off <<= 1) z += __shfl_xor(z, off);
        float rz = 1.f / z;
        float acc0 = 0.f, acc1 = 0.f;
        for (int i = r0; i < r1; i += 8) {
            int cnt = r1 - i;
            unsigned cc[8]; float ww[8];
#pragma unroll
            for (int j = 0; j < 8; j++) {
                if (j < cnt) {
                    cc[j] = *(const unsigned*)(s + (size_t)src_s[i + j] * 384 + 256 + 2 * lane);
                    ww[j] = expf(evals[2 * (i + j) + h1] - mm) * rz;
                } else { cc[j] = 0u; ww[j] = 0.f; }
            }
#pragma unroll
            for (int j = 0; j < 8; j++) {
                acc0 = fmaf(ww[j], bfl(cc[j]), acc0);
                acc1 = fmaf(ww[j], bfh(cc[j]), acc1);
            }
        }
        *aout = (unsigned)f2bf(acc0) | ((unsigned)f2bf(acc1) << 16);
    }
}

// ---------------- node MLP + residual, MFMA: h' = gelu(agg@W1+b1)@W2+b2 + h ----------------
__global__ __launch_bounds__(256) void k_mlp(
    const bf16_t* __restrict__ aggb, const bf16_t* __restrict__ W1T, const float* __restrict__ b1,
    const bf16_t* __restrict__ W2T, const float* __restrict__ b2,
    const float* __restrict__ hin, float* __restrict__ hout, bf16_t* __restrict__ houtb,
    float* __restrict__ out, int col0)
{
    __shared__ __align__(16) bf16_t aggS[32 * 136];
    __shared__ __align__(16) bf16_t hidS[32 * 136];
    const int t = threadIdx.x;
    const int wave = t >> 6, lane = t & 63, l16 = lane & 15, quad = lane >> 4;
    const int n0 = blockIdx.x * 32;
    {   // stage agg tile: 32 rows x 256B (32B per thread)
        int r = t >> 3, sg = t & 7;
        *(s16x8*)(aggS + r * 136 + sg * 16) =
            *(const s16x8*)(aggb + (size_t)(n0 + r) * 128 + sg * 16);
        *(s16x8*)(aggS + r * 136 + sg * 16 + 8) =
            *(const s16x8*)(aggb + (size_t)(n0 + r) * 128 + sg * 16 + 8);
    }
    __syncthreads();
    const int ng = wave & 1, nh = wave >> 1;
    const int node = n0 + ng * 16 + l16;
    {   // GEMM1 + gelu -> hidS
        const bf16_t* brow = aggS + (ng * 16 + l16) * 136 + quad * 8;
        s16x8 B[4];
#pragma unroll
        for (int ks = 0; ks < 4; ks++) B[ks] = *(const s16x8*)(brow + ks * 32);
#pragma unroll
        for (int nt = 0; nt < 4; nt++) {
            int nb = nh * 64 + nt * 16;
            f32x4 acc = {0.f, 0.f, 0.f, 0.f};
#pragma unroll
            for (int ks = 0; ks < 4; ks++) {
                const s16x8 A = *(const s16x8*)(W1T + (size_t)(nb + l16) * 128 + ks * 32 + quad * 8);
                acc = __builtin_amdgcn_mfma_f32_16x16x32_bf16(A, B[ks], acc, 0, 0, 0);
            }
            const float4 bv = *(const float4*)(b1 + nb + quad * 4);
            ushort4 o;
            o.x = f2bf(gelu_f(acc[0] + bv.x));
            o.y = f2bf(gelu_f(acc[1] + bv.y));
            o.z = f2bf(gelu_f(acc[2] + bv.z));
            o.w = f2bf(gelu_f(acc[3] + bv.w));
            *(ushort4*)(hidS + (ng * 16 + l16) * 136 + nb + quad * 4) = o;
        }
    }
    __syncthreads();
    {   // GEMM2 + bias + residual -> hout/houtb/out
        const int jh = wave >> 1;
        const bf16_t* hrow = hidS + (ng * 16 + l16) * 136 + quad * 8;
        s16x8 H[4];
#pragma unroll
        for (int ks = 0; ks < 4; ks++) H[ks] = *(const s16x8*)(hrow + ks * 32);
#pragma unroll
        for (int jt = 0; jt < 2; jt++) {
            int jb = jh * 32 + jt * 16;
            f32x4 acc = {0.f, 0.f, 0.f, 0.f};
#pragma unroll
            for (int ks = 0; ks < 4; ks++) {
                const s16x8 A = *(const s16x8*)(W2T + (size_t)(jb + l16) * 128 + ks * 32 + quad * 8);
                acc = __builtin_amdgcn_mfma_f32_16x16x32_bf16(A, H[ks], acc, 0, 0, 0);
            }
            int j0 = jb + quad * 4;
            const float4 bv = *(const float4*)(b2 + j0);
            const float4 hv = *(const float4*)(hin + (size_t)node * 64 + j0);
            float4 v;
            v.x = acc[0] + bv.x + hv.x;
            v.y = acc[1] + bv.y + hv.y;
            v.z = acc[2] + bv.z + hv.z;
            v.w = acc[3] + bv.w + hv.w;
            *(float4*)(hout + (size_t)node * 64 + j0) = v;
            ushort4 ob;
            ob.x = f2bf(v.x); ob.y = f2bf(v.y); ob.z = f2bf(v.z); ob.w = f2bf(v.w);
            *(ushort4*)(houtb + (size_t)node * 64 + j0) = ob;
            if (node < N_NODES)
                *(float4*)(out + (size_t)node * 704 + col0 + j0) = v;
        }
    }
}

// ---------------- graph max pooling over node_emb cols 0..351 ----------------
__device__ __forceinline__ unsigned fmap(float v) {
    unsigned u = __float_as_uint(v);
    return (u & 0x80000000u) ? ~u : (u | 0x80000000u);
}

__global__ __launch_bounds__(384) void k_colmax(const float* __restrict__ out, unsigned* __restrict__ gmax) {
    int c = threadIdx.x;
    if (c >= 352) return;
    float m = -1e30f;
    for (int n = blockIdx.x; n < N_NODES; n += gridDim.x)
        m = fmaxf(m, out[(size_t)n * 704 + c]);
    atomicMax(gmax + c, fmap(m));
}

__global__ __launch_bounds__(384) void k_bcast(const unsigned* __restrict__ gmax, float* __restrict__ out) {
    int c = threadIdx.x;
    if (c >= 352) return;
    unsigned u = gmax[c];
    u = (u & 0x80000000u) ? (u ^ 0x80000000u) : ~u;
    float v = __uint_as_float(u);
    for (int n = blockIdx.x; n < N_NODES; n += gridDim.x)
        out[(size_t)n * 704 + 352 + c] = v;
}

// ---------------- host launcher ----------------
extern "C" void kernel_launch(void* const* d_in, const int* in_sizes, int n_in,
                              void* d_out, int out_size, void* d_ws, size_t ws_size,
                              hipStream_t stream)
{
    (void)in_sizes; (void)n_in; (void)out_size; (void)ws_size;
    const float* feat     = (const float*)d_in[0];
    const float* att_rc   = (const float*)d_in[1];
    const float* att_rp   = (const float*)d_in[2];
    const float* type_emb = (const float*)d_in[3];
    const float* rid_emb  = (const float*)d_in[4];
    const float* rc_W     = (const float*)d_in[5];
    const float* rc_b     = (const float*)d_in[6];
    const float* rp_W     = (const float*)d_in[7];
    const float* rp_b     = (const float*)d_in[8];
    const float* fe_W1    = (const float*)d_in[9];
    const float* fe_b1    = (const float*)d_in[10];
    const float* fe_W2    = (const float*)d_in[11];
    const float* fe_b2    = (const float*)d_in[12];
    const float* W_ni     = (const float*)d_in[13];
    const float* W_nj     = (const float*)d_in[14];
    const float* W_fij    = (const float*)d_in[15];
    const float* W_node   = (const float*)d_in[16];
    const float* b_node   = (const float*)d_in[17];
    const float* attn     = (const float*)d_in[18];
    const float* mlp_W1   = (const float*)d_in[19];
    const float* mlp_b1   = (const float*)d_in[20];
    const float* mlp_W2   = (const float*)d_in[21];
    const float* mlp_b2   = (const float*)d_in[22];
    const int* src   = (const int*)d_in[23];
    const int* dst   = (const int*)d_in[24];
    const int* etype = (const int*)d_in[25];
    const int* erid  = (const int*)d_in[26];
    float* out = (float*)d_out;

    // Workspace layout (byte cursor, all chunks 16B aligned). Footprint ~= R0 (+80 KB).
    char* cur = (char*)d_ws;
    auto alloc = [&](size_t bytes) { char* p = cur; cur += (bytes + 15) & ~(size_t)15; return p; };
    float* h_a    = (float*)alloc((size_t)NPAD * 64 * 4);
    float* h_b    = (float*)alloc((size_t)NPAD * 64 * 4);
    bf16_t* hb_a  = (bf16_t*)alloc((size_t)NPAD * 64 * 2);
    bf16_t* hb_b  = (bf16_t*)alloc((size_t)NPAD * 64 * 2);
    bf16_t* s     = (bf16_t*)alloc((size_t)NPAD * 384 * 2);
    float* ev     = (float*)alloc((size_t)N_EDGES * 2 * 4);
    bf16_t* aggb  = (bf16_t*)alloc((size_t)NPAD * 128 * 2);
    int* deg     = (int*)alloc((size_t)N_NODES * 4);
    int* rowptr  = (int*)alloc((size_t)(N_NODES + 1) * 4);
    int* cursor  = (int*)alloc((size_t)N_NODES * 4);
    int* eidx    = (int*)alloc((size_t)N_EDGES * 4);
    int* src_s   = (int*)alloc((size_t)N_EDGES * 4);
    uint4* emeta = (uint4*)alloc((size_t)N_EDGES * 32);
    float* baseT = (float*)alloc((size_t)315 * 64 * 4);
    bf16_t* WT   = (bf16_t*)alloc((size_t)NLAYER * 128 * 64 * 2);
    bf16_t* W3T  = (bf16_t*)alloc((size_t)NLAYER * 384 * 64 * 2);
    bf16_t* W1T  = (bf16_t*)alloc((size_t)NLAYER * 128 * 128 * 2);
    bf16_t* W2T  = (bf16_t*)alloc((size_t)NLAYER * 64 * 128 * 2);
    int* bsum    = (int*)alloc(64 * 4);
    int* boff    = (int*)alloc(64 * 4);
    unsigned* gmax = (unsigned*)alloc(352 * 4);

    const int NB = (N_NODES + 1023) / 1024;  // 49

    k_zero32<<<(N_NODES + 255) / 256, 256, 0, stream>>>((unsigned*)deg, N_NODES);
    k_zero32<<<2, 256, 0, stream>>>(gmax, 352);
    k_hist<<<N_EDGES / 256, 256, 0, stream>>>(dst, deg);
    k_scan1<<<NB, 1024, 0, stream>>>(deg, rowptr, bsum);
    k_scan2<<<1, 64, 0, stream>>>(bsum, boff, NB);
    k_scan3<<<NB, 1024, 0, stream>>>(rowptr, boff);
    k_copy<<<(N_NODES + 255) / 256, 256, 0, stream>>>(rowptr, cursor);
    k_scatter<<<N_EDGES / 256, 256, 0, stream>>>(dst, cursor, eidx);
    k_sortgather<<<N_EDGES / 256, 256, 0, stream>>>(eidx, src, dst, etype, erid, att_rc, att_rp,
                                                    src_s, emeta);
    k_base<<<(315 * 64 + 255) / 256, 256, 0, stream>>>(type_emb, rid_emb, rc_b, rp_b, baseT);
    k_wprep<<<(NLAYER * 57344 + 255) / 256, 256, 0, stream>>>(
        W_fij, W_ni, W_nj, W_node, mlp_W1, mlp_W2, WT, W3T, W1T, W2T);
    k_fe<<<N_NODES / 4, 256, 0, stream>>>(feat, fe_W1, fe_b1, fe_W2, fe_b2, h_a, hb_a, out);

    float* hc = h_a;  bf16_t* hbc = hb_a;
    float* hn = h_b;  bf16_t* hbn = hb_b;
    for (int l = 0; l < NLAYER; l++) {
        k_node3<<<NPAD / 32, 256, 0, stream>>>(hbc, W3T + (size_t)l * 384 * 64, b_node + l * 128, s);
        k_edge<<<2560, 256, 0, stream>>>(s, WT + l * 128 * 64, attn + l * 128, emeta, baseT,
                                         rc_W, rp_W, ev);
        k_soft_agg<<<4096, 256, 0, stream>>>(rowptr, src_s, ev, s, (unsigned*)aggb);
        k_mlp<<<NPAD / 32, 256, 0, stream>>>(aggb, W1T + (size_t)l * 128 * 128, mlp_b1 + l * 128,
                                             W2T + (size_t)l * 64 * 128, mlp_b2 + l * 64,
                                             hc, hn, hbn, out, 32 + 64 * (l + 1));
        float* tf = hc; hc = hn; hn = tf;
        bf16_t* tb = hbc; hbc = hbn; hbn = tb;
    }
    k_colmax<<<512, 384, 0, stream>>>(out, gmax);
    k_bcast<<<512, 384, 0, stream>>>(gmax, out);
}